// Round 3
// baseline (571.774 us; speedup 1.0000x reference)
//
#include <hip/hip_runtime.h>

#define BATCH  4096
#define HIDDEN 2048
#define INPUT  2048
#define KDIM   4096   // INPUT + HIDDEN (fused K)
#define NDIM   8192   // 4 * HIDDEN (fused gate dim), gate-interleaved: n' = 4*j + g
#define BM 128
#define BN 128
#define BK 32
#define EPI_STRIDE 36   // LDS epilogue tile stride (words): bank=(4*row+jg)%32 -> conflict-free

typedef __attribute__((ext_vector_type(8))) short short8;
typedef __attribute__((ext_vector_type(4))) float float4v;

// ---------- helpers ----------

__device__ __forceinline__ unsigned short f2bf(float f) {
    union { float f; unsigned u; } v; v.f = f;
    unsigned r = v.u + 0x7FFFu + ((v.u >> 16) & 1u);   // round-to-nearest-even
    return (unsigned short)(r >> 16);
}

__device__ __forceinline__ void gl2lds16(const unsigned short* g, unsigned short* l) {
    __builtin_amdgcn_global_load_lds(
        (const __attribute__((address_space(1))) unsigned int*)g,
        (__attribute__((address_space(3))) unsigned int*)l,
        16, 0, 0);
}

__device__ __forceinline__ float sigm(float x) {
    return 1.0f / (1.0f + __expf(-x));
}
__device__ __forceinline__ float tanh_fast(float x) {
    return 2.0f / (1.0f + __expf(-2.0f * x)) - 1.0f;
}

// ---------- kernel 1: combined pack ----------
// blocks [0, 8192):    pack [x|h] -> Xb bf16, row-major K-contiguous
// blocks [8192, 24576): pack/transpose W' -> Wt bf16 B^T, gate-interleaved n'=4*j+g

__global__ void pack_kernel(const float* __restrict__ x, const float* __restrict__ h,
                            const float* __restrict__ w_ih, const float* __restrict__ w_hh,
                            unsigned short* __restrict__ Xb, unsigned short* __restrict__ Wt) {
    __shared__ float tile[64][33];
    int bid = blockIdx.x;
    if (bid < 8192) {
        // ---- pack_x ----
        int idx = bid * 256 + threadIdx.x;      // one 8-element group per thread
        int b  = idx >> 9;                      // 512 groups per row (4096/8)
        int ko = idx & 511;
        const float* src = (ko < 256) ? (x + (size_t)b * INPUT  + (size_t)ko * 8)
                                      : (h + (size_t)b * HIDDEN + (size_t)(ko - 256) * 8);
        float4 v0 = *(const float4*)(src);
        float4 v1 = *(const float4*)(src + 4);
        union { unsigned short us[8]; uint4 v; } o;
        o.us[0] = f2bf(v0.x); o.us[1] = f2bf(v0.y); o.us[2] = f2bf(v0.z); o.us[3] = f2bf(v0.w);
        o.us[4] = f2bf(v1.x); o.us[5] = f2bf(v1.y); o.us[6] = f2bf(v1.z); o.us[7] = f2bf(v1.w);
        *(uint4*)(Xb + (size_t)b * KDIM + (size_t)ko * 8) = o.v;
    } else {
        // ---- pack_w ----
        int wb = bid - 8192;
        int k0 = (wb & 63) * 64;     // K tile (never straddles the 2048 boundary)
        int n0 = (wb >> 6) * 32;     // source-N tile (never straddles a gate boundary)
        int g  = n0 >> 11;
        int j0 = n0 & 2047;
        const float* src = (k0 < INPUT)
            ? (w_ih + (size_t)g * INPUT  * HIDDEN + (size_t)k0 * HIDDEN + j0)
            : (w_hh + (size_t)g * HIDDEN * HIDDEN + (size_t)(k0 - INPUT) * HIDDEN + j0);

        int tcol = threadIdx.x & 31;      // j within tile
        int trow = threadIdx.x >> 5;      // 0..7
#pragma unroll
        for (int p = 0; p < 8; ++p)
            tile[trow + p * 8][tcol] = src[(size_t)(trow + p * 8) * HIDDEN + tcol];
        __syncthreads();

        int tk = threadIdx.x & 63;        // k within tile
        int tn = threadIdx.x >> 6;        // 0..3
#pragma unroll
        for (int p = 0; p < 8; ++p) {
            int j = j0 + tn + p * 4;
            Wt[(size_t)(4 * j + g) * KDIM + k0 + tk] = f2bf(tile[tk][tn + p * 4]);
        }
    }
}

// ---------- kernel 2: bf16 MFMA GEMM + fused LSTM epilogue (LDS-coalesced) ----------

__global__ __launch_bounds__(256, 2)
void gemm_kernel(const unsigned short* __restrict__ A,
                 const unsigned short* __restrict__ B,
                 const float* __restrict__ c,
                 const float* __restrict__ b_ih,
                 const float* __restrict__ b_hh,
                 float* __restrict__ out) {
    // smem: [0,8192) As | [8192,16384) Bs  during K-loop
    //       [0,18432) hT | [18432,36864) cT  during epilogue (stride-36 float tiles)
    __shared__ __align__(16) char smem[2 * 128 * EPI_STRIDE * 4];
    unsigned short* As = (unsigned short*)smem;
    unsigned short* Bs = (unsigned short*)(smem + 8192);
    float* hT = (float*)smem;
    float* cT = (float*)(smem + 128 * EPI_STRIDE * 4);

    const int tid  = threadIdx.x;
    const int m0   = blockIdx.y * BM;
    const int n0   = blockIdx.x * BN;
    const int jg0  = n0 >> 2;
    const int wave = tid >> 6;
    const int lane = tid & 63;
    const int ln   = lane & 15;
    const int kq   = lane >> 4;             // 0..3
    const int wm   = (wave >> 1) * 64;
    const int wn   = (wave & 1) * 64;
    const int q    = lane & 3;              // gate index pre-transpose / row sub-offset post
    const int t    = (lane & 15) >> 2;      // j sub-offset

    // staging: tile = 512 segments of 16 B; thread handles segments tid, tid+256
    const int s0 = tid, s1 = tid + 256;
    const unsigned short* gA0 = A + (size_t)(m0 + (s0 >> 2)) * KDIM + (s0 & 3) * 8;
    const unsigned short* gA1 = A + (size_t)(m0 + (s1 >> 2)) * KDIM + (s1 & 3) * 8;
    const unsigned short* gB0 = B + (size_t)(n0 + (s0 >> 2)) * KDIM + (s0 & 3) * 8;
    const unsigned short* gB1 = B + (size_t)(n0 + (s1 >> 2)) * KDIM + (s1 & 3) * 8;
    unsigned short* lA0 = As + s0 * 8;
    unsigned short* lA1 = As + s1 * 8;
    unsigned short* lB0 = Bs + s0 * 8;
    unsigned short* lB1 = Bs + s1 * 8;

    float4v acc[4][4];
#pragma unroll
    for (int i = 0; i < 4; ++i)
#pragma unroll
        for (int j = 0; j < 4; ++j)
            acc[i][j] = (float4v){0.f, 0.f, 0.f, 0.f};

    // ---- prefetch c + biases into registers (no GEMM dependency; hidden by K-loop) ----
    float cv[4][4];     // [mi][ni] : c for this lane's post-transpose element
    float bsum[4][4];   // [ni][g]  : b_ih + b_hh
#pragma unroll
    for (int mi = 0; mi < 4; ++mi) {
        const int row = m0 + wm + mi * 16 + kq * 4 + q;
#pragma unroll
        for (int ni = 0; ni < 4; ++ni)
            cv[mi][ni] = c[(size_t)row * HIDDEN + jg0 + (wn >> 2) + ni * 4 + t];
    }
#pragma unroll
    for (int ni = 0; ni < 4; ++ni) {
        const int jg = jg0 + (wn >> 2) + ni * 4 + t;
#pragma unroll
        for (int g = 0; g < 4; ++g)
            bsum[ni][g] = b_ih[g * HIDDEN + jg] + b_hh[g * HIDDEN + jg];
    }

    const int a_off = (wm + ln) * BK + kq * 8;   // + mi*16*BK
    const int b_off = (wn + ln) * BK + kq * 8;   // + ni*16*BK

    for (int kt = 0; kt < KDIM / BK; ++kt) {
        const int ko = kt * BK;
        gl2lds16(gA0 + ko, lA0);
        gl2lds16(gA1 + ko, lA1);
        gl2lds16(gB0 + ko, lB0);
        gl2lds16(gB1 + ko, lB1);
        __syncthreads();

        short8 af[4], bfr[4];
#pragma unroll
        for (int mi = 0; mi < 4; ++mi)
            af[mi] = *(const short8*)(As + a_off + mi * 16 * BK);
#pragma unroll
        for (int ni = 0; ni < 4; ++ni)
            bfr[ni] = *(const short8*)(Bs + b_off + ni * 16 * BK);

#pragma unroll
        for (int mi = 0; mi < 4; ++mi)
#pragma unroll
            for (int ni = 0; ni < 4; ++ni)
                acc[mi][ni] = __builtin_amdgcn_mfma_f32_16x16x32_bf16(
                    af[mi], bfr[ni], acc[mi][ni], 0, 0, 0);

        __syncthreads();
    }

    // ---- fused epilogue ----
    // C/D layout: col = ln, row = kq*4 + reg. col n' = 4*j + g with g = ln&3.
    // Quad transpose (shfl_xor 1 then 2): lane q ends with gates 0..3 of row-offset kq*4+q.
#pragma unroll
    for (int ni = 0; ni < 4; ++ni) {
        const int jgL = (wn >> 2) + ni * 4 + t;   // local jg in [0,32)
#pragma unroll
        for (int mi = 0; mi < 4; ++mi) {
            float4v v = acc[mi][ni];
            // round 1: xor 1, exchange reg pairs (0,1) and (2,3)
            float t1 = __shfl_xor((q & 1) ? v[0] : v[1], 1);
            float t2 = __shfl_xor((q & 1) ? v[2] : v[3], 1);
            v[0] = (q & 1) ? t1 : v[0];
            v[1] = (q & 1) ? v[1] : t1;
            v[2] = (q & 1) ? t2 : v[2];
            v[3] = (q & 1) ? v[3] : t2;
            // round 2: xor 2, exchange reg pairs (0,2) and (1,3)
            float t3 = __shfl_xor((q & 2) ? v[0] : v[2], 2);
            float t4 = __shfl_xor((q & 2) ? v[1] : v[3], 2);
            v[0] = (q & 2) ? t3 : v[0];
            v[1] = (q & 2) ? t4 : v[1];
            v[2] = (q & 2) ? v[2] : t3;
            v[3] = (q & 2) ? v[3] : t4;

            const int rowL = wm + mi * 16 + kq * 4 + q;   // local row in [0,128)
            const float ig = sigm(v[0] + bsum[ni][0]);
            const float fg = sigm(v[1] + bsum[ni][1]);
            const float cg = tanh_fast(v[2] + bsum[ni][2]);
            const float og = sigm(v[3] + bsum[ni][3]);
            const float cn = fg * cv[mi][ni] + ig * cg;
            const float hn = og * tanh_fast(cn);
            hT[rowL * EPI_STRIDE + jgL] = hn;
            cT[rowL * EPI_STRIDE + jgL] = cn;
        }
    }
    __syncthreads();

    // ---- coalesced write-out: 1024 segments of 16 B per tile, 4 per thread ----
    const size_t HB = (size_t)BATCH * HIDDEN;
#pragma unroll
    for (int p = 0; p < 4; ++p) {
        const int s   = tid + p * 256;
        const int row = s >> 3;
        const int c4  = s & 7;
        float4 hv = *(const float4*)(hT + row * EPI_STRIDE + c4 * 4);
        float4 cw = *(const float4*)(cT + row * EPI_STRIDE + c4 * 4);
        const size_t go = (size_t)(m0 + row) * HIDDEN + jg0 + c4 * 4;
        *(float4*)(out + go)      = hv;   // h_new
        *(float4*)(out + HB + go) = cw;   // c_new
    }
}

// ---------- launcher ----------

extern "C" void kernel_launch(void* const* d_in, const int* in_sizes, int n_in,
                              void* d_out, int out_size, void* d_ws, size_t ws_size,
                              hipStream_t stream) {
    const float* x    = (const float*)d_in[0];
    const float* h    = (const float*)d_in[1];
    const float* c    = (const float*)d_in[2];
    const float* w_ih = (const float*)d_in[3];
    const float* w_hh = (const float*)d_in[4];
    const float* b_ih = (const float*)d_in[5];
    const float* b_hh = (const float*)d_in[6];
    float* out = (float*)d_out;

    const size_t XB_BYTES = (size_t)BATCH * KDIM * 2;   // 32 MB
    unsigned short* Xb = (unsigned short*)d_ws;
    unsigned short* Wt = (unsigned short*)((char*)d_ws + XB_BYTES);  // 64 MB

    hipLaunchKernelGGL(pack_kernel, dim3(8192 + 16384), dim3(256), 0, stream,
                       x, h, w_ih, w_hh, Xb, Wt);
    hipLaunchKernelGGL(gemm_kernel, dim3(NDIM / BN, BATCH / BM), dim3(256), 0, stream,
                       Xb, Wt, c, b_ih, b_hh, out);
}